// Round 20
// baseline (1566.532 us; speedup 1.0000x reference)
//
#include <hip/hip_runtime.h>
#include <hip/hip_bf16.h>

#define NEGF (-1000000000.0f)

namespace {

constexpr int B  = 64;
constexpr int N  = 50;
constexpr int NT = 30;
constexpr int T  = 60;
constexpr int S  = 90;          // NT + T
constexpr int NP1 = N + 1;      // 51
constexpr int NSMAX = N - 1;    // 49
constexpr int SS = S * S;       // 8100
constexpr int CELLSP = NSMAX * 32 + 32;  // padded cells (stride 32 per span)
constexpr int ECOUNT = B * NP1 * NP1 * S;

// ---- padded K layout (BYTES: fp8 = 1 B/element) ----
constexpr int KP  = 96;          // padded r-dim per l (pads are exact 0)
constexpr int KK  = S * KP;      // 8640 elements = bytes
constexpr int KSPL = 27;         // split-K chunks (R20: was 15; shorter chains)
constexpr int KT2B = 64;         // K-tile bytes per row slice
constexpr int NKT = KK / KT2B;   // 135
constexpr int TPC = NKT / KSPL;  // 5 tiles per chunk
constexpr int ROWB  = 72;        // stage2 LDS row stride bytes
constexpr int AOFFB = 32 * ROWB;
constexpr int MTOTB = (32 + 64) * ROWB;       // 6912 B per buffer

// ---- stage1 MFMA layout (bf16 internal) ----
constexpr int S1R = 96;          // padded state rows: 6 tiles of 16
constexpr int S1STR = 72;        // row stride in shorts (144B, b128-aligned)

using bf16x8 = __attribute__((ext_vector_type(8))) short;
using f32x4  = __attribute__((ext_vector_type(4))) float;

__device__ __forceinline__ unsigned int pk4_e4m3(float a, float b, float c, float d){
  int w = __builtin_amdgcn_cvt_pk_fp8_f32(a, b, 0, false);
  w = __builtin_amdgcn_cvt_pk_fp8_f32(c, d, w, true);
  return (unsigned int)w;
}
__device__ __forceinline__ short f2bs(float v){
  __hip_bfloat16 h = __float2bfloat16(v);
  return *reinterpret_cast<short*>(&h);
}

// width-1 spans: mb = state max; E_L/E_R = bf16(exp(unary - mb)) terminal slots.
__global__ void unary_init(const float* __restrict__ unary, float* __restrict__ mb,
                           short* __restrict__ E_L, short* __restrict__ E_R){
  int k = blockIdx.x, b = blockIdx.y, j = threadIdx.x;
  float v = (j < T) ? unary[(b*N + k)*T + j] : NEGF;
  float m = v;
  #pragma unroll
  for (int off = 32; off > 0; off >>= 1) m = fmaxf(m, __shfl_xor(m, off));
  if (j == 0) mb[(b*NP1 + k)*NP1 + (k+1)] = m;
  if (j < T){
    short sv = f2bs(__expf(v - m));
    E_L[((size_t)((b*NP1 + k)*NP1 + (k+1)))*S + NT + j] = sv;
    E_R[((size_t)((b*NP1 + (k+1))*NP1 + k))*S + NT + j] = sv;
  }
}

// 2-pass rule prep -> fp8 e4m3; also emr = exp(m_rule) for stage1's finalize.
__global__ __launch_bounds__(256) void rule_prep(const float* __restrict__ rule,
                                                 float* __restrict__ m_rule,
                                                 float* __restrict__ emr,
                                                 unsigned char* __restrict__ erule8){
  int p = blockIdx.x, b = blockIdx.y, tid = threadIdx.x;
  size_t base = (size_t)(b*NT + p) * SS;
  size_t obase = (size_t)(b*NT + p) * KK;
  const float4* r4 = (const float4*)(rule + base);
  float lm = NEGF;
  for (int i = tid; i < SS/4; i += 256){
    float4 v = r4[i];
    lm = fmaxf(fmaxf(lm, fmaxf(v.x, v.y)), fmaxf(v.z, v.w));
  }
  #pragma unroll
  for (int off = 32; off > 0; off >>= 1) lm = fmaxf(lm, __shfl_xor(lm, off));
  __shared__ float wmax[4];
  __shared__ float sm;
  if ((tid & 63) == 0) wmax[tid >> 6] = lm;
  __syncthreads();
  if (tid == 0){
    float m = fmaxf(fmaxf(wmax[0], wmax[1]), fmaxf(wmax[2], wmax[3]));
    m_rule[b*NT + p] = m;
    emr[b*NT + p] = __expf(m);
    sm = m;
  }
  __syncthreads();
  float m = sm;
  for (int idx = tid; idx < S * 24; idx += 256){
    int l = idx / 24, q4 = idx - l * 24;
    int r = q4 * 4;
    float e[4];
    #pragma unroll
    for (int j = 0; j < 4; ++j){
      int rr = r + j;
      e[j] = (rr < S) ? __expf(rule[base + l*S + rr] - m) : 0.f;
    }
    *(unsigned int*)&erule8[obase + l*KP + r] = pk4_e4m3(e[0], e[1], e[2], e[3]);
  }
}

// Per span (b,s) of width w: O[l,r] = sum_k el[k,l]*er[k,r] via bf16 MFMA.
// Inline finalize of width-(w-1) (R18) + XOR k-swizzled staging (R19).
__global__ __launch_bounds__(256) void stage1(int w, int ns,
                                              const float* __restrict__ Cpart,
                                              const float* __restrict__ emr,
                                              const float* __restrict__ MbufPrev,
                                              float* __restrict__ MbufCur,
                                              short* __restrict__ E_L,
                                              short* __restrict__ E_R,
                                              float* __restrict__ mb,
                                              unsigned char* __restrict__ Og8){
  int s = blockIdx.x, b = blockIdx.y, e = s + w, tid = threadIdx.x;
  int K = w - 1;
  int Kpad = (K + 31) & ~31;          // 32 or 64
  int kmask = (Kpad >> 3) - 1;        // 3 or 7
  __shared__ float stmp[NSMAX];
  __shared__ float cK[NSMAX];
  __shared__ float sM;
  __shared__ float qs[2][32];
  __shared__ float cmax[2];
  __shared__ float cmb[2];
  __shared__ __align__(16) short sbuf[2 * S1R * S1STR];  // 27.6 KB
  short* elT = sbuf;
  short* erT = sbuf + S1R * S1STR;

  bool hasInline = (w >= 3);
  if (hasInline){
    // inline finalize of width-(w-1) cells sp=s (c=0) and sp=s+1 (c=1)
    for (int idx = tid; idx < 2*NT; idx += 256){
      int c = (idx >= NT) ? 1 : 0;
      int p = idx - c*NT;
      int sp = s + c;
      float sum = 0.f;
      #pragma unroll
      for (int kc = 0; kc < KSPL; ++kc)
        sum += Cpart[((size_t)(kc*B + b))*CELLSP + sp*32 + p];
      qs[c][p] = sum * emr[b*NT + p];
    }
  }
  __syncthreads();
  if (hasInline && tid < 2){
    float m = 1e-37f;
    for (int p = 0; p < NT; ++p) m = fmaxf(m, qs[tid][p]);
    cmax[tid] = m;
    cmb[tid] = MbufPrev[b*NSMAX + (s + tid)] + __logf(m);
  }
  __syncthreads();

  if (hasInline){
    // writer duty for future launches (values deterministic across blocks)
    int wp = w - 1;
    if (tid < 15){
      float inv = 1.f / cmax[0];
      unsigned int pk = (unsigned int)(unsigned short)f2bs(qs[0][2*tid] * inv) |
                        ((unsigned int)(unsigned short)f2bs(qs[0][2*tid+1] * inv) << 16);
      *(unsigned int*)&E_L[((size_t)((b*NP1 + s)*NP1 + s + wp))*S + 2*tid] = pk;
      *(unsigned int*)&E_R[((size_t)((b*NP1 + s + wp)*NP1 + s))*S + 2*tid] = pk;
    } else if (tid >= 32 && tid < 47 && s == ns - 1){
      int t2 = tid - 32;
      float inv = 1.f / cmax[1];
      unsigned int pk = (unsigned int)(unsigned short)f2bs(qs[1][2*t2] * inv) |
                        ((unsigned int)(unsigned short)f2bs(qs[1][2*t2+1] * inv) << 16);
      *(unsigned int*)&E_L[((size_t)((b*NP1 + s + 1)*NP1 + s + 1 + wp))*S + 2*t2] = pk;
      *(unsigned int*)&E_R[((size_t)((b*NP1 + s + 1 + wp)*NP1 + s + 1))*S + 2*t2] = pk;
    }
    if (tid == 0) mb[(b*NP1 + s)*NP1 + (s + wp)] = cmb[0];
    if (tid == 16 && s == ns - 1) mb[(b*NP1 + s + 1)*NP1 + (s + 1 + wp)] = cmb[1];
  }

  if (tid < K){
    int u = s + tid + 1;
    float ml = (hasInline && tid == K - 1) ? cmb[0] : mb[(b*NP1 + s)*NP1 + u];
    float mr = (hasInline && tid == 0)     ? cmb[1] : mb[(b*NP1 + u)*NP1 + e];
    stmp[tid] = ml + mr;
  }
  __syncthreads();
  if (tid == 0){
    float M = NEGF;
    for (int k = 0; k < K; ++k) M = fmaxf(M, stmp[k]);
    sM = M;
    MbufCur[b*NSMAX + s] = M;
  }
  __syncthreads();
  float M = sM;
  if (tid < K) cK[tid] = __expf(stmp[tid] - M);
  __syncthreads();

  // contiguous bases: left children rows (s,u) u=s+1..s+K; right rows (u,e)
  const short* baseL = E_L + ((size_t)((b*NP1 + s)*NP1 + s + 1)) * S;
  const short* baseR = E_R + ((size_t)((b*NP1 + e)*NP1 + s + 1)) * S;

  int items = Kpad * 48;               // 48 uint pairs per k (45 data + 3 pad)
  for (int idx = tid; idx < items; idx += 256){
    int k = idx / 48, j = idx - k * 48;
    int i = 2 * j;
    short v0 = 0, v1 = 0, r0 = 0, r1 = 0;
    if (k < K && j < 45){
      // pair j<15 -> i<30 (nonterminals); j>=15 -> i>=30 (terminals)
      bool lOK = (k == 0)     ? (j >= 15) : (j < 15);
      bool rOK = (k == K - 1) ? (j >= 15) : (j < 15);
      float ck = cK[k];
      if (lOK){
        float f0, f1;
        if (hasInline && k == K - 1){
          float inv = 1.f / cmax[0];
          f0 = qs[0][i] * inv * ck;
          f1 = qs[0][i+1] * inv * ck;
        } else {
          unsigned int L = *(const unsigned int*)(baseL + k*S + i);
          f0 = __uint_as_float(L << 16) * ck;
          f1 = __uint_as_float(L & 0xFFFF0000u) * ck;
        }
        v0 = f2bs(f0);
        v1 = f2bs(f1);
      }
      if (rOK){
        if (hasInline && k == 0){
          float inv = 1.f / cmax[1];
          r0 = f2bs(qs[1][i] * inv);
          r1 = f2bs(qs[1][i+1] * inv);
        } else {
          unsigned int R = *(const unsigned int*)(baseR + k*S + i);
          r0 = (short)(R & 0xFFFFu);
          r1 = (short)(R >> 16);
        }
      }
    }
    // swizzled column: block (k>>3) ^ ((i>>1)&kmask); rows i,i+1 share i>>1
    int kk7 = k & 7;
    int swc = (((k >> 3) ^ ((i >> 1) & kmask)) << 3) + kk7;
    elT[i*S1STR + swc]     = v0;
    elT[(i+1)*S1STR + swc] = v1;
    erT[i*S1STR + swc]     = r0;
    erT[(i+1)*S1STR + swc] = r1;
  }
  __syncthreads();

  int wid = tid >> 6, lane = tid & 63;
  int rr = lane & 15, hi = lane >> 4;
  int ksteps = Kpad >> 5;
  f32x4 accs[9];
  #pragma unroll
  for (int j = 0; j < 9; ++j){           // 36 tiles over 4 waves
    int t = wid * 9 + j;
    int tr = t / 6, tc = t - tr * 6;
    int ar = tr*16 + rr, br = tc*16 + rr;
    f32x4 acc = {0.f, 0.f, 0.f, 0.f};
    for (int ks = 0; ks < ksteps; ++ks){
      int kb = ks*4 + hi;
      bf16x8 af = *(bf16x8*)&elT[ar*S1STR + ((kb ^ ((ar >> 1) & kmask)) << 3)];
      bf16x8 bf2 = *(bf16x8*)&erT[br*S1STR + ((kb ^ ((br >> 1) & kmask)) << 3)];
      acc = __builtin_amdgcn_mfma_f32_16x16x32_bf16(af, bf2, acc, 0, 0, 0);
    }
    accs[j] = acc;
  }
  __syncthreads();                        // all elT/erT reads done; sbuf reusable

  // repack: fp8 O tile, linear [l*96 + r] bytes in sbuf, then uint4 stores
  unsigned char* rep = (unsigned char*)sbuf;
  for (int idx = tid; idx < S * (KP - S); idx += 256){
    int l = idx / (KP - S), c = idx - l * (KP - S);
    rep[l*KP + S + c] = 0;
  }
  #pragma unroll
  for (int j = 0; j < 9; ++j){
    int t = wid * 9 + j;
    int tr = t / 6, tc = t - tr * 6;
    int rcol = tc*16 + rr;
    if (rcol < S){
      unsigned int pk = pk4_e4m3(accs[j][0], accs[j][1], accs[j][2], accs[j][3]);
      #pragma unroll
      for (int q = 0; q < 4; ++q){
        int l = tr*16 + hi*4 + q;
        if (l < S) rep[l*KP + rcol] = (unsigned char)((pk >> (8*q)) & 0xff);
      }
    }
  }
  __syncthreads();

  size_t obase = ((size_t)(b*NSMAX + s)) * KK;
  uint4* dst = (uint4*)(Og8 + obase);
  const uint4* src = (const uint4*)rep;
  for (int i = tid; i < KK/16; i += 256) dst[i] = src[i];
}

// fp8 MFMA split-K GEMM; no LDS zero-fill (clamped rows -> discarded slots).
__global__ __launch_bounds__(512) void stage2(int ns, int ntiles,
                                              const unsigned char* __restrict__ erule8,
                                              const unsigned char* __restrict__ Og8,
                                              float* __restrict__ Cpart){
  int kc = blockIdx.x, b = blockIdx.y, tid = threadIdx.x;
  __shared__ __align__(16) unsigned char ldsb[2 * MTOTB];   // 13.8 KB (dbuf)
  int wid = tid >> 6, lane = tid & 63;
  int mt = wid & 1, nt = wid >> 1;
  f32x4 acc = {0.f, 0.f, 0.f, 0.f};

  int slot = tid & 7;
  int aRow = (tid >> 3) & 31;
  int aRowS = aRow < NT ? aRow : NT - 1;      // clamp: rows 30,31 replicate 29
  bool aDo = (tid < 256);
  int bRow = tid >> 3;
  int bRowS = bRow < ns ? bRow : ns - 1;      // clamp
  const unsigned char* aSrc = erule8 + ((size_t)(b*NT + aRowS)) * KK + slot * 8;
  const unsigned char* bSrc = Og8    + ((size_t)(b*NSMAX + bRowS)) * KK + slot * 8;
  int aOff = aRow * ROWB + slot * 8;
  int bOff = AOFFB + bRow * ROWB + slot * 8;

  int arow = mt*16 + (lane & 15);
  int brow = nt*16 + (lane & 15);
  int hi = lane >> 4;
  bool active = nt < ntiles;
  int t0 = kc * TPC;

  uint2 ra, rb;
  if (aDo) ra = *(const uint2*)(aSrc + (size_t)t0 * KT2B);
  rb = *(const uint2*)(bSrc + (size_t)t0 * KT2B);

  int cur = 0;
  for (int tt = 0; tt < TPC; ++tt){
    if (aDo) *(uint2*)&ldsb[cur*MTOTB + aOff] = ra;
    *(uint2*)&ldsb[cur*MTOTB + bOff] = rb;
    if (tt + 1 < TPC){
      size_t koff = (size_t)(t0 + tt + 1) * KT2B;
      if (aDo) ra = *(const uint2*)(aSrc + koff);
      rb = *(const uint2*)(bSrc + koff);
    }
    __syncthreads();   // buf[cur] staged; compute(tt-1) on buf[cur^1] done
    if (active){
      #pragma unroll
      for (int ks = 0; ks < 2; ++ks){
        int sb = ks*4 + hi;
        long af = *(const long*)&ldsb[cur*MTOTB + arow*ROWB + sb*8];
        long bf2 = *(const long*)&ldsb[cur*MTOTB + AOFFB + brow*ROWB + sb*8];
        acc = __builtin_amdgcn_mfma_f32_16x16x32_fp8_fp8(af, bf2, acc, 0, 0, 0);
      }
    }
    cur ^= 1;
  }

  if (active){
    int scol = nt*16 + (lane & 15);
    if (scol < ns){
      int p0 = mt*16 + hi*4;           // acc[r] -> p = p0 + r (contiguous)
      float* cp = Cpart + ((size_t)(kc*B + b)) * CELLSP + scol*32 + p0;
      *(f32x4*)cp = acc;               // p=30,31 overflow lands in padding
    }
  }
}

// Root: beta(w=50) computed directly from Cpart (ns=1: cell = p).
__global__ void root_lse(const float* __restrict__ Cpart, const float* __restrict__ Mbuf,
                         const float* __restrict__ m_rule, const float* __restrict__ root,
                         float* __restrict__ out){
  int b = blockIdx.x, j = threadIdx.x;
  float v = NEGF;
  if (j < NT){
    float sum = 0.f;
    #pragma unroll
    for (int q = 0; q < KSPL; ++q)
      sum += Cpart[((size_t)(q*B + b))*CELLSP + j];
    v = __logf(fmaxf(sum, 1e-37f)) + Mbuf[b*NSMAX + 0]
      + m_rule[b*NT + j] + root[b*NT + j];
  }
  float m = v;
  #pragma unroll
  for (int off = 32; off > 0; off >>= 1) m = fmaxf(m, __shfl_xor(m, off));
  float ex = __expf(v - m);
  #pragma unroll
  for (int off = 32; off > 0; off >>= 1) ex += __shfl_xor(ex, off);
  if (j == 0) out[b] = __logf(ex) + m;
}

} // namespace

extern "C" void kernel_launch(void* const* d_in, const int* in_sizes, int n_in,
                              void* d_out, int out_size, void* d_ws, size_t ws_size,
                              hipStream_t stream){
  (void)in_sizes; (void)n_in; (void)out_size; (void)ws_size;
  const float* unary = (const float*)d_in[0];
  const float* rule  = (const float*)d_in[1];
  const float* root  = (const float*)d_in[2];

  char* ws = (char*)d_ws;
  size_t off = 0;
  auto alloc = [&](size_t bytes) -> void* {
    void* p = ws + off;
    off += (bytes + 255) & ~(size_t)255;
    return p;
  };
  float* mb     = (float*)alloc(sizeof(float) * (size_t)B * NP1 * NP1);
  float* m_rule = (float*)alloc(sizeof(float) * B * NT);
  float* emr    = (float*)alloc(sizeof(float) * B * NT);
  float* Mbuf   = (float*)alloc(sizeof(float) * 2 * B * NSMAX);   // parity dbuf
  float* Cpart  = (float*)alloc(sizeof(float) * KSPL * B * CELLSP);  // 11 MB
  short* E_L    = (short*)alloc(sizeof(short) * (size_t)ECOUNT);     // 30 MB
  short* E_R    = (short*)alloc(sizeof(short) * (size_t)ECOUNT);     // 30 MB
  unsigned char* erule8 = (unsigned char*)alloc((size_t)B * NT * KK);    // 16.6 MB
  unsigned char* Og8    = (unsigned char*)alloc((size_t)B * NSMAX * KK); // 27.1 MB

  unary_init<<<dim3(N, B), dim3(64), 0, stream>>>(unary, mb, E_L, E_R);
  rule_prep<<<dim3(NT, B), dim3(256), 0, stream>>>(rule, m_rule, emr, erule8);

  for (int w = 2; w <= N; ++w){
    int ns = N - w + 1;
    int ntiles = (ns + 15) >> 4;
    const float* mprev = Mbuf + ((size_t)((w - 1) & 1)) * B * NSMAX;
    float*       mcur  = Mbuf + ((size_t)(w & 1)) * B * NSMAX;
    stage1<<<dim3(ns, B), dim3(256), 0, stream>>>(w, ns, Cpart, emr,
                                                  mprev, mcur, E_L, E_R, mb, Og8);
    stage2<<<dim3(KSPL, B), dim3(512), 0, stream>>>(ns, ntiles, erule8, Og8, Cpart);
  }
  // w=50 parity: 50&1 == 0 -> Mbuf first half holds M for width 50
  root_lse<<<dim3(B), dim3(64), 0, stream>>>(Cpart, Mbuf, m_rule, root, (float*)d_out);
}

// Round 21
// 1455.422 us; speedup vs baseline: 1.0763x; 1.0763x over previous
//
#include <hip/hip_runtime.h>
#include <hip/hip_bf16.h>

#define NEGF (-1000000000.0f)

namespace {

constexpr int B  = 64;
constexpr int N  = 50;
constexpr int NT = 30;
constexpr int T  = 60;
constexpr int S  = 90;          // NT + T
constexpr int NP1 = N + 1;      // 51
constexpr int NSMAX = N - 1;    // 49
constexpr int SS = S * S;       // 8100
constexpr int CELLSP = NSMAX * 32 + 32;  // padded cells (stride 32 per span)
constexpr int ECOUNT = B * NP1 * NP1 * S;

// ---- padded K layout (BYTES: fp8 = 1 B/element) ----
constexpr int KP  = 96;          // padded r-dim per l (pads are exact 0)
constexpr int KK  = S * KP;      // 8640 elements = bytes
constexpr int KSPL = 15;         // split-K chunks (R19 champion config)
constexpr int KT2B = 64;         // K-tile bytes per row slice
constexpr int NKT = KK / KT2B;   // 135
constexpr int TPC = NKT / KSPL;  // 9 tiles per chunk
constexpr int ROWB  = 72;        // stage2 LDS row stride bytes
constexpr int AOFFB = 32 * ROWB;
constexpr int MTOTB = (32 + 64) * ROWB;       // 6912 B per buffer

// ---- stage1 MFMA layout (bf16 internal) ----
constexpr int S1R = 96;          // padded state rows: 6 tiles of 16
constexpr int S1STR = 72;        // row stride in shorts (144B, b128-aligned)

using bf16x8 = __attribute__((ext_vector_type(8))) short;
using s16x4  = __attribute__((ext_vector_type(4))) short;
using f32x4  = __attribute__((ext_vector_type(4))) float;

__device__ __forceinline__ unsigned int pk4_e4m3(float a, float b, float c, float d){
  int w = __builtin_amdgcn_cvt_pk_fp8_f32(a, b, 0, false);
  w = __builtin_amdgcn_cvt_pk_fp8_f32(c, d, w, true);
  return (unsigned int)w;
}
__device__ __forceinline__ short f2bs(float v){
  __hip_bfloat16 h = __float2bfloat16(v);
  return *reinterpret_cast<short*>(&h);
}

// width-1 spans: mb = state max; E_L/E_R = bf16(exp(unary - mb)) terminal slots.
__global__ void unary_init(const float* __restrict__ unary, float* __restrict__ mb,
                           short* __restrict__ E_L, short* __restrict__ E_R){
  int k = blockIdx.x, b = blockIdx.y, j = threadIdx.x;
  float v = (j < T) ? unary[(b*N + k)*T + j] : NEGF;
  float m = v;
  #pragma unroll
  for (int off = 32; off > 0; off >>= 1) m = fmaxf(m, __shfl_xor(m, off));
  if (j == 0) mb[(b*NP1 + k)*NP1 + (k+1)] = m;
  if (j < T){
    short sv = f2bs(__expf(v - m));
    E_L[((size_t)((b*NP1 + k)*NP1 + (k+1)))*S + NT + j] = sv;
    E_R[((size_t)((b*NP1 + (k+1))*NP1 + k))*S + NT + j] = sv;
  }
}

// 2-pass rule prep -> fp8 e4m3; emr = exp(m_rule) for stage1's inline finalize.
__global__ __launch_bounds__(256) void rule_prep(const float* __restrict__ rule,
                                                 float* __restrict__ m_rule,
                                                 float* __restrict__ emr,
                                                 unsigned char* __restrict__ erule8){
  int p = blockIdx.x, b = blockIdx.y, tid = threadIdx.x;
  size_t base = (size_t)(b*NT + p) * SS;
  size_t obase = (size_t)(b*NT + p) * KK;
  const float4* r4 = (const float4*)(rule + base);
  float lm = NEGF;
  for (int i = tid; i < SS/4; i += 256){
    float4 v = r4[i];
    lm = fmaxf(fmaxf(lm, fmaxf(v.x, v.y)), fmaxf(v.z, v.w));
  }
  #pragma unroll
  for (int off = 32; off > 0; off >>= 1) lm = fmaxf(lm, __shfl_xor(lm, off));
  __shared__ float wmax[4];
  __shared__ float sm;
  if ((tid & 63) == 0) wmax[tid >> 6] = lm;
  __syncthreads();
  if (tid == 0){
    float m = fmaxf(fmaxf(wmax[0], wmax[1]), fmaxf(wmax[2], wmax[3]));
    m_rule[b*NT + p] = m;
    emr[b*NT + p] = __expf(m);
    sm = m;
  }
  __syncthreads();
  float m = sm;
  for (int idx = tid; idx < S * 24; idx += 256){
    int l = idx / 24, q4 = idx - l * 24;
    int r = q4 * 4;
    float e[4];
    #pragma unroll
    for (int j = 0; j < 4; ++j){
      int rr = r + j;
      e[j] = (rr < S) ? __expf(rule[base + l*S + rr] - m) : 0.f;
    }
    *(unsigned int*)&erule8[obase + l*KP + r] = pk4_e4m3(e[0], e[1], e[2], e[3]);
  }
}

// Per span (b,s) of width w: O[l,r] = sum_k el[k,l]*er[k,r] via bf16 MFMA.
// Inline finalize of width-(w-1) (R18) + XOR k-block swizzle (R19).
// R21: staging regrouped to (i-pair x k-quad) -> ds_write_b64 (half the
// LDS write instructions; conflict-stall cycles ~halve).
__global__ __launch_bounds__(256) void stage1(int w, int ns,
                                              const float* __restrict__ Cpart,
                                              const float* __restrict__ emr,
                                              const float* __restrict__ MbufPrev,
                                              float* __restrict__ MbufCur,
                                              short* __restrict__ E_L,
                                              short* __restrict__ E_R,
                                              float* __restrict__ mb,
                                              unsigned char* __restrict__ Og8){
  int s = blockIdx.x, b = blockIdx.y, e = s + w, tid = threadIdx.x;
  int K = w - 1;
  int Kpad = (K + 31) & ~31;          // 32 or 64
  int kmask = (Kpad >> 3) - 1;        // 3 or 7
  __shared__ float stmp[NSMAX];
  __shared__ float cK[NSMAX];
  __shared__ float sM;
  __shared__ float qs[2][32];
  __shared__ float cmax[2];
  __shared__ float cmb[2];
  __shared__ __align__(16) short sbuf[2 * S1R * S1STR];  // 27.6 KB
  short* elT = sbuf;
  short* erT = sbuf + S1R * S1STR;

  bool hasInline = (w >= 3);
  if (hasInline){
    // inline finalize of width-(w-1) cells sp=s (c=0) and sp=s+1 (c=1)
    for (int idx = tid; idx < 2*NT; idx += 256){
      int c = (idx >= NT) ? 1 : 0;
      int p = idx - c*NT;
      int sp = s + c;
      float sum = 0.f;
      #pragma unroll
      for (int kc = 0; kc < KSPL; ++kc)
        sum += Cpart[((size_t)(kc*B + b))*CELLSP + sp*32 + p];
      qs[c][p] = sum * emr[b*NT + p];
    }
  }
  __syncthreads();
  if (hasInline && tid < 2){
    float m = 1e-37f;
    for (int p = 0; p < NT; ++p) m = fmaxf(m, qs[tid][p]);
    cmax[tid] = m;
    cmb[tid] = MbufPrev[b*NSMAX + (s + tid)] + __logf(m);
  }
  __syncthreads();

  if (hasInline){
    // writer duty for future launches (values deterministic across blocks)
    int wp = w - 1;
    if (tid < 15){
      float inv = 1.f / cmax[0];
      unsigned int pk = (unsigned int)(unsigned short)f2bs(qs[0][2*tid] * inv) |
                        ((unsigned int)(unsigned short)f2bs(qs[0][2*tid+1] * inv) << 16);
      *(unsigned int*)&E_L[((size_t)((b*NP1 + s)*NP1 + s + wp))*S + 2*tid] = pk;
      *(unsigned int*)&E_R[((size_t)((b*NP1 + s + wp)*NP1 + s))*S + 2*tid] = pk;
    } else if (tid >= 32 && tid < 47 && s == ns - 1){
      int t2 = tid - 32;
      float inv = 1.f / cmax[1];
      unsigned int pk = (unsigned int)(unsigned short)f2bs(qs[1][2*t2] * inv) |
                        ((unsigned int)(unsigned short)f2bs(qs[1][2*t2+1] * inv) << 16);
      *(unsigned int*)&E_L[((size_t)((b*NP1 + s + 1)*NP1 + s + 1 + wp))*S + 2*t2] = pk;
      *(unsigned int*)&E_R[((size_t)((b*NP1 + s + 1 + wp)*NP1 + s + 1))*S + 2*t2] = pk;
    }
    if (tid == 0) mb[(b*NP1 + s)*NP1 + (s + wp)] = cmb[0];
    if (tid == 16 && s == ns - 1) mb[(b*NP1 + s + 1)*NP1 + (s + 1 + wp)] = cmb[1];
  }

  if (tid < K){
    int u = s + tid + 1;
    float ml = (hasInline && tid == K - 1) ? cmb[0] : mb[(b*NP1 + s)*NP1 + u];
    float mr = (hasInline && tid == 0)     ? cmb[1] : mb[(b*NP1 + u)*NP1 + e];
    stmp[tid] = ml + mr;
  }
  __syncthreads();
  if (tid == 0){
    float M = NEGF;
    for (int k = 0; k < K; ++k) M = fmaxf(M, stmp[k]);
    sM = M;
    MbufCur[b*NSMAX + s] = M;
  }
  __syncthreads();
  float M = sM;
  if (tid < K) cK[tid] = __expf(stmp[tid] - M);
  __syncthreads();

  // contiguous bases: left children rows (s,u) u=s+1..s+K; right rows (u,e)
  const short* baseL = E_L + ((size_t)((b*NP1 + s)*NP1 + s + 1)) * S;
  const short* baseR = E_R + ((size_t)((b*NP1 + e)*NP1 + s + 1)) * S;

  // staging: thread handles (k-quad kq, i-pair j) -> 4 x ds_write_b64
  int items = (Kpad >> 2) * 48;
  for (int idx = tid; idx < items; idx += 256){
    int kq = idx / 48, j = idx - kq * 48;
    int i = 2 * j;
    s16x4 el0 = {0,0,0,0}, el1 = {0,0,0,0}, er0 = {0,0,0,0}, er1 = {0,0,0,0};
    if (j < 45){
      #pragma unroll
      for (int kk = 0; kk < 4; ++kk){
        int k = 4*kq + kk;
        if (k < K){
          bool lOK = (k == 0)     ? (j >= 15) : (j < 15);
          bool rOK = (k == K - 1) ? (j >= 15) : (j < 15);
          float ck = cK[k];
          if (lOK){
            float f0, f1;
            if (hasInline && k == K - 1){
              float inv = 1.f / cmax[0];
              f0 = qs[0][i] * inv * ck;
              f1 = qs[0][i+1] * inv * ck;
            } else {
              unsigned int L = *(const unsigned int*)(baseL + k*S + i);
              f0 = __uint_as_float(L << 16) * ck;
              f1 = __uint_as_float(L & 0xFFFF0000u) * ck;
            }
            el0[kk] = f2bs(f0);
            el1[kk] = f2bs(f1);
          }
          if (rOK){
            if (hasInline && k == 0){
              float inv = 1.f / cmax[1];
              er0[kk] = f2bs(qs[1][i] * inv);
              er1[kk] = f2bs(qs[1][i+1] * inv);
            } else {
              unsigned int R = *(const unsigned int*)(baseR + k*S + i);
              er0[kk] = (short)(R & 0xFFFFu);
              er1[kk] = (short)(R >> 16);
            }
          }
        }
      }
    }
    // swizzled position: block (kbase>>3) ^ (j & kmask); sub-offset kbase&7
    int kbase = 4 * kq;
    int swp = ((((kbase >> 3) ^ (j & kmask)) << 3) + (kbase & 7));
    *(s16x4*)&elT[i*S1STR + swp]     = el0;
    *(s16x4*)&elT[(i+1)*S1STR + swp] = el1;
    *(s16x4*)&erT[i*S1STR + swp]     = er0;
    *(s16x4*)&erT[(i+1)*S1STR + swp] = er1;
  }
  __syncthreads();

  int wid = tid >> 6, lane = tid & 63;
  int rr = lane & 15, hi = lane >> 4;
  int ksteps = Kpad >> 5;
  f32x4 accs[9];
  #pragma unroll
  for (int j = 0; j < 9; ++j){           // 36 tiles over 4 waves
    int t = wid * 9 + j;
    int tr = t / 6, tc = t - tr * 6;
    int ar = tr*16 + rr, br = tc*16 + rr;
    f32x4 acc = {0.f, 0.f, 0.f, 0.f};
    for (int ks = 0; ks < ksteps; ++ks){
      int kb = ks*4 + hi;
      bf16x8 af = *(bf16x8*)&elT[ar*S1STR + ((kb ^ ((ar >> 1) & kmask)) << 3)];
      bf16x8 bf2 = *(bf16x8*)&erT[br*S1STR + ((kb ^ ((br >> 1) & kmask)) << 3)];
      acc = __builtin_amdgcn_mfma_f32_16x16x32_bf16(af, bf2, acc, 0, 0, 0);
    }
    accs[j] = acc;
  }
  __syncthreads();                        // all elT/erT reads done; sbuf reusable

  // repack: fp8 O tile, linear [l*96 + r] bytes in sbuf, then uint4 stores
  unsigned char* rep = (unsigned char*)sbuf;
  for (int idx = tid; idx < S * (KP - S); idx += 256){
    int l = idx / (KP - S), c = idx - l * (KP - S);
    rep[l*KP + S + c] = 0;
  }
  #pragma unroll
  for (int j = 0; j < 9; ++j){
    int t = wid * 9 + j;
    int tr = t / 6, tc = t - tr * 6;
    int rcol = tc*16 + rr;
    if (rcol < S){
      unsigned int pk = pk4_e4m3(accs[j][0], accs[j][1], accs[j][2], accs[j][3]);
      #pragma unroll
      for (int q = 0; q < 4; ++q){
        int l = tr*16 + hi*4 + q;
        if (l < S) rep[l*KP + rcol] = (unsigned char)((pk >> (8*q)) & 0xff);
      }
    }
  }
  __syncthreads();

  size_t obase = ((size_t)(b*NSMAX + s)) * KK;
  uint4* dst = (uint4*)(Og8 + obase);
  const uint4* src = (const uint4*)rep;
  for (int i = tid; i < KK/16; i += 256) dst[i] = src[i];
}

// fp8 MFMA split-K GEMM; no LDS zero-fill (clamped rows -> discarded slots).
__global__ __launch_bounds__(512) void stage2(int ns, int ntiles,
                                              const unsigned char* __restrict__ erule8,
                                              const unsigned char* __restrict__ Og8,
                                              float* __restrict__ Cpart){
  int kc = blockIdx.x, b = blockIdx.y, tid = threadIdx.x;
  __shared__ __align__(16) unsigned char ldsb[2 * MTOTB];   // 13.8 KB (dbuf)
  int wid = tid >> 6, lane = tid & 63;
  int mt = wid & 1, nt = wid >> 1;
  f32x4 acc = {0.f, 0.f, 0.f, 0.f};

  int slot = tid & 7;
  int aRow = (tid >> 3) & 31;
  int aRowS = aRow < NT ? aRow : NT - 1;      // clamp: rows 30,31 replicate 29
  bool aDo = (tid < 256);
  int bRow = tid >> 3;
  int bRowS = bRow < ns ? bRow : ns - 1;      // clamp
  const unsigned char* aSrc = erule8 + ((size_t)(b*NT + aRowS)) * KK + slot * 8;
  const unsigned char* bSrc = Og8    + ((size_t)(b*NSMAX + bRowS)) * KK + slot * 8;
  int aOff = aRow * ROWB + slot * 8;
  int bOff = AOFFB + bRow * ROWB + slot * 8;

  int arow = mt*16 + (lane & 15);
  int brow = nt*16 + (lane & 15);
  int hi = lane >> 4;
  bool active = nt < ntiles;
  int t0 = kc * TPC;

  uint2 ra, rb;
  if (aDo) ra = *(const uint2*)(aSrc + (size_t)t0 * KT2B);
  rb = *(const uint2*)(bSrc + (size_t)t0 * KT2B);

  int cur = 0;
  for (int tt = 0; tt < TPC; ++tt){
    if (aDo) *(uint2*)&ldsb[cur*MTOTB + aOff] = ra;
    *(uint2*)&ldsb[cur*MTOTB + bOff] = rb;
    if (tt + 1 < TPC){
      size_t koff = (size_t)(t0 + tt + 1) * KT2B;
      if (aDo) ra = *(const uint2*)(aSrc + koff);
      rb = *(const uint2*)(bSrc + koff);
    }
    __syncthreads();   // buf[cur] staged; compute(tt-1) on buf[cur^1] done
    if (active){
      #pragma unroll
      for (int ks = 0; ks < 2; ++ks){
        int sb = ks*4 + hi;
        long af = *(const long*)&ldsb[cur*MTOTB + arow*ROWB + sb*8];
        long bf2 = *(const long*)&ldsb[cur*MTOTB + AOFFB + brow*ROWB + sb*8];
        acc = __builtin_amdgcn_mfma_f32_16x16x32_fp8_fp8(af, bf2, acc, 0, 0, 0);
      }
    }
    cur ^= 1;
  }

  if (active){
    int scol = nt*16 + (lane & 15);
    if (scol < ns){
      int p0 = mt*16 + hi*4;           // acc[r] -> p = p0 + r (contiguous)
      float* cp = Cpart + ((size_t)(kc*B + b)) * CELLSP + scol*32 + p0;
      *(f32x4*)cp = acc;               // p=30,31 overflow lands in padding
    }
  }
}

// Root: beta(w=50) computed directly from Cpart (ns=1: cell = p).
__global__ void root_lse(const float* __restrict__ Cpart, const float* __restrict__ Mbuf,
                         const float* __restrict__ m_rule, const float* __restrict__ root,
                         float* __restrict__ out){
  int b = blockIdx.x, j = threadIdx.x;
  float v = NEGF;
  if (j < NT){
    float sum = 0.f;
    #pragma unroll
    for (int q = 0; q < KSPL; ++q)
      sum += Cpart[((size_t)(q*B + b))*CELLSP + j];
    v = __logf(fmaxf(sum, 1e-37f)) + Mbuf[b*NSMAX + 0]
      + m_rule[b*NT + j] + root[b*NT + j];
  }
  float m = v;
  #pragma unroll
  for (int off = 32; off > 0; off >>= 1) m = fmaxf(m, __shfl_xor(m, off));
  float ex = __expf(v - m);
  #pragma unroll
  for (int off = 32; off > 0; off >>= 1) ex += __shfl_xor(ex, off);
  if (j == 0) out[b] = __logf(ex) + m;
}

} // namespace

extern "C" void kernel_launch(void* const* d_in, const int* in_sizes, int n_in,
                              void* d_out, int out_size, void* d_ws, size_t ws_size,
                              hipStream_t stream){
  (void)in_sizes; (void)n_in; (void)out_size; (void)ws_size;
  const float* unary = (const float*)d_in[0];
  const float* rule  = (const float*)d_in[1];
  const float* root  = (const float*)d_in[2];

  char* ws = (char*)d_ws;
  size_t off = 0;
  auto alloc = [&](size_t bytes) -> void* {
    void* p = ws + off;
    off += (bytes + 255) & ~(size_t)255;
    return p;
  };
  float* mb     = (float*)alloc(sizeof(float) * (size_t)B * NP1 * NP1);
  float* m_rule = (float*)alloc(sizeof(float) * B * NT);
  float* emr    = (float*)alloc(sizeof(float) * B * NT);
  float* Mbuf   = (float*)alloc(sizeof(float) * 2 * B * NSMAX);   // parity dbuf
  float* Cpart  = (float*)alloc(sizeof(float) * KSPL * B * CELLSP);  // 6.1 MB
  short* E_L    = (short*)alloc(sizeof(short) * (size_t)ECOUNT);     // 30 MB
  short* E_R    = (short*)alloc(sizeof(short) * (size_t)ECOUNT);     // 30 MB
  unsigned char* erule8 = (unsigned char*)alloc((size_t)B * NT * KK);    // 16.6 MB
  unsigned char* Og8    = (unsigned char*)alloc((size_t)B * NSMAX * KK); // 27.1 MB

  unary_init<<<dim3(N, B), dim3(64), 0, stream>>>(unary, mb, E_L, E_R);
  rule_prep<<<dim3(NT, B), dim3(256), 0, stream>>>(rule, m_rule, emr, erule8);

  for (int w = 2; w <= N; ++w){
    int ns = N - w + 1;
    int ntiles = (ns + 15) >> 4;
    const float* mprev = Mbuf + ((size_t)((w - 1) & 1)) * B * NSMAX;
    float*       mcur  = Mbuf + ((size_t)(w & 1)) * B * NSMAX;
    stage1<<<dim3(ns, B), dim3(256), 0, stream>>>(w, ns, Cpart, emr,
                                                  mprev, mcur, E_L, E_R, mb, Og8);
    stage2<<<dim3(KSPL, B), dim3(512), 0, stream>>>(ns, ntiles, erule8, Og8, Cpart);
  }
  // w=50 parity: 50&1 == 0 -> Mbuf first half holds M for width 50
  root_lse<<<dim3(B), dim3(64), 0, stream>>>(Cpart, Mbuf, m_rule, root, (float*)d_out);
}

// Round 22
// 1408.807 us; speedup vs baseline: 1.1120x; 1.0331x over previous
//
#include <hip/hip_runtime.h>
#include <hip/hip_bf16.h>

#define NEGF (-1000000000.0f)

namespace {

constexpr int B  = 64;
constexpr int N  = 50;
constexpr int NT = 30;
constexpr int T  = 60;
constexpr int S  = 90;          // NT + T
constexpr int NP1 = N + 1;      // 51
constexpr int NSMAX = N - 1;    // 49
constexpr int SS = S * S;       // 8100
constexpr int CELLSP = NSMAX * 32 + 32;  // padded cells (stride 32 per span)
constexpr int ECOUNT = B * NP1 * NP1 * S;

// ---- padded K layout (BYTES: fp8 = 1 B/element) ----
constexpr int KP  = 96;          // padded r-dim per l (pads are exact 0)
constexpr int KK  = S * KP;      // 8640 elements = bytes
constexpr int KSPL = 15;         // split-K chunks
constexpr int KT2B = 64;         // K-tile bytes per row slice
constexpr int NKT = KK / KT2B;   // 135
constexpr int TPC = NKT / KSPL;  // 9 tiles per chunk
constexpr int ROWB  = 72;        // stage2 LDS row stride bytes
constexpr int AOFFB = 32 * ROWB;
constexpr int MTOTB = (32 + 64) * ROWB;       // 6912 B per buffer

// ---- stage1 MFMA layout (bf16 internal) ----
constexpr int S1R = 96;          // padded state rows: 6 tiles of 16
constexpr int S1STR = 72;        // row stride in shorts (144B, b128-aligned)

using bf16x8 = __attribute__((ext_vector_type(8))) short;
using s16x4  = __attribute__((ext_vector_type(4))) short;
using f32x4  = __attribute__((ext_vector_type(4))) float;

__device__ __forceinline__ unsigned int pk4_e4m3(float a, float b, float c, float d){
  int w = __builtin_amdgcn_cvt_pk_fp8_f32(a, b, 0, false);
  w = __builtin_amdgcn_cvt_pk_fp8_f32(c, d, w, true);
  return (unsigned int)w;
}
__device__ __forceinline__ short f2bs(float v){
  __hip_bfloat16 h = __float2bfloat16(v);
  return *reinterpret_cast<short*>(&h);
}

// width-1 spans: mb/mbT = state max; E_L/E_R = bf16(exp(unary - mb)).
__global__ void unary_init(const float* __restrict__ unary, float* __restrict__ mb,
                           float* __restrict__ mbT,
                           short* __restrict__ E_L, short* __restrict__ E_R){
  int k = blockIdx.x, b = blockIdx.y, j = threadIdx.x;
  float v = (j < T) ? unary[(b*N + k)*T + j] : NEGF;
  float m = v;
  #pragma unroll
  for (int off = 32; off > 0; off >>= 1) m = fmaxf(m, __shfl_xor(m, off));
  if (j == 0){
    mb [(b*NP1 + k)*NP1 + (k+1)] = m;
    mbT[(b*NP1 + (k+1))*NP1 + k] = m;
  }
  if (j < T){
    short sv = f2bs(__expf(v - m));
    E_L[((size_t)((b*NP1 + k)*NP1 + (k+1)))*S + NT + j] = sv;
    E_R[((size_t)((b*NP1 + (k+1))*NP1 + k))*S + NT + j] = sv;
  }
}

// 2-pass rule prep -> fp8 e4m3; emr = exp(m_rule) for stage1's inline finalize.
__global__ __launch_bounds__(256) void rule_prep(const float* __restrict__ rule,
                                                 float* __restrict__ m_rule,
                                                 float* __restrict__ emr,
                                                 unsigned char* __restrict__ erule8){
  int p = blockIdx.x, b = blockIdx.y, tid = threadIdx.x;
  size_t base = (size_t)(b*NT + p) * SS;
  size_t obase = (size_t)(b*NT + p) * KK;
  const float4* r4 = (const float4*)(rule + base);
  float lm = NEGF;
  for (int i = tid; i < SS/4; i += 256){
    float4 v = r4[i];
    lm = fmaxf(fmaxf(lm, fmaxf(v.x, v.y)), fmaxf(v.z, v.w));
  }
  #pragma unroll
  for (int off = 32; off > 0; off >>= 1) lm = fmaxf(lm, __shfl_xor(lm, off));
  __shared__ float wmax[4];
  __shared__ float sm;
  if ((tid & 63) == 0) wmax[tid >> 6] = lm;
  __syncthreads();
  if (tid == 0){
    float m = fmaxf(fmaxf(wmax[0], wmax[1]), fmaxf(wmax[2], wmax[3]));
    m_rule[b*NT + p] = m;
    emr[b*NT + p] = __expf(m);
    sm = m;
  }
  __syncthreads();
  float m = sm;
  for (int idx = tid; idx < S * 24; idx += 256){
    int l = idx / 24, q4 = idx - l * 24;
    int r = q4 * 4;
    float e[4];
    #pragma unroll
    for (int j = 0; j < 4; ++j){
      int rr = r + j;
      e[j] = (rr < S) ? __expf(rule[base + l*S + rr] - m) : 0.f;
    }
    *(unsigned int*)&erule8[obase + l*KP + r] = pk4_e4m3(e[0], e[1], e[2], e[3]);
  }
}

// Per span (b,s) of width w: O[l,r] = sum_k el[k,l]*er[k,r] via bf16 MFMA.
// R22: contiguous mr gather via mbT; wave-parallel shfl reductions for
// cmax/M (replaces single-thread 30/49-iteration serial loops).
__global__ __launch_bounds__(256) void stage1(int w, int ns,
                                              const float* __restrict__ Cpart,
                                              const float* __restrict__ emr,
                                              const float* __restrict__ MbufPrev,
                                              float* __restrict__ MbufCur,
                                              short* __restrict__ E_L,
                                              short* __restrict__ E_R,
                                              float* __restrict__ mb,
                                              float* __restrict__ mbT,
                                              unsigned char* __restrict__ Og8){
  int s = blockIdx.x, b = blockIdx.y, e = s + w, tid = threadIdx.x;
  int K = w - 1;
  int Kpad = (K + 31) & ~31;          // 32 or 64
  int kmask = (Kpad >> 3) - 1;        // 3 or 7
  __shared__ float stmp[NSMAX];
  __shared__ float cK[NSMAX];
  __shared__ float sM;
  __shared__ float qs[2][32];
  __shared__ float cmax[2];
  __shared__ float cmb[2];
  __shared__ __align__(16) short sbuf[2 * S1R * S1STR];  // 27.6 KB
  short* elT = sbuf;
  short* erT = sbuf + S1R * S1STR;

  bool hasInline = (w >= 3);
  if (hasInline){
    // inline finalize of width-(w-1) cells sp=s (c=0) and sp=s+1 (c=1)
    for (int idx = tid; idx < 2*NT; idx += 256){
      int c = (idx >= NT) ? 1 : 0;
      int p = idx - c*NT;
      int sp = s + c;
      float sum = 0.f;
      #pragma unroll
      for (int kc = 0; kc < KSPL; ++kc)
        sum += Cpart[((size_t)(kc*B + b))*CELLSP + sp*32 + p];
      qs[c][p] = sum * emr[b*NT + p];
    }
  }
  __syncthreads();
  if (hasInline && tid < 64){
    // lanes 0-31 reduce qs[0], lanes 32-63 reduce qs[1] (xor offsets < 32)
    int half = tid >> 5, p = tid & 31;
    float v = (p < NT) ? qs[half][p] : 1e-37f;
    #pragma unroll
    for (int off = 16; off > 0; off >>= 1) v = fmaxf(v, __shfl_xor(v, off));
    if (p == 0){
      cmax[half] = v;
      cmb[half] = MbufPrev[b*NSMAX + (s + half)] + __logf(v);
    }
  }
  __syncthreads();

  if (hasInline){
    // writer duty for future launches (values deterministic across blocks)
    int wp = w - 1;
    if (tid < 15){
      float inv = 1.f / cmax[0];
      unsigned int pk = (unsigned int)(unsigned short)f2bs(qs[0][2*tid] * inv) |
                        ((unsigned int)(unsigned short)f2bs(qs[0][2*tid+1] * inv) << 16);
      *(unsigned int*)&E_L[((size_t)((b*NP1 + s)*NP1 + s + wp))*S + 2*tid] = pk;
      *(unsigned int*)&E_R[((size_t)((b*NP1 + s + wp)*NP1 + s))*S + 2*tid] = pk;
    } else if (tid >= 32 && tid < 47 && s == ns - 1){
      int t2 = tid - 32;
      float inv = 1.f / cmax[1];
      unsigned int pk = (unsigned int)(unsigned short)f2bs(qs[1][2*t2] * inv) |
                        ((unsigned int)(unsigned short)f2bs(qs[1][2*t2+1] * inv) << 16);
      *(unsigned int*)&E_L[((size_t)((b*NP1 + s + 1)*NP1 + s + 1 + wp))*S + 2*t2] = pk;
      *(unsigned int*)&E_R[((size_t)((b*NP1 + s + 1 + wp)*NP1 + s + 1))*S + 2*t2] = pk;
    }
    if (tid == 0){
      mb [(b*NP1 + s)*NP1 + (s + wp)] = cmb[0];
      mbT[(b*NP1 + s + wp)*NP1 + s]   = cmb[0];
    }
    if (tid == 16 && s == ns - 1){
      mb [(b*NP1 + s + 1)*NP1 + (s + 1 + wp)] = cmb[1];
      mbT[(b*NP1 + s + 1 + wp)*NP1 + (s + 1)] = cmb[1];
    }
  }

  if (tid < K){
    int u = s + tid + 1;
    // both gathers contiguous in u: mb row s, mbT row e
    float ml = (hasInline && tid == K - 1) ? cmb[0] : mb [(b*NP1 + s)*NP1 + u];
    float mr = (hasInline && tid == 0)     ? cmb[1] : mbT[(b*NP1 + e)*NP1 + u];
    stmp[tid] = ml + mr;
  }
  __syncthreads();
  if (tid < 64){
    float v = (tid < K) ? stmp[tid] : NEGF;
    #pragma unroll
    for (int off = 32; off > 0; off >>= 1) v = fmaxf(v, __shfl_xor(v, off));
    if (tid == 0){
      sM = v;
      MbufCur[b*NSMAX + s] = v;
    }
  }
  __syncthreads();
  float M = sM;
  if (tid < K) cK[tid] = __expf(stmp[tid] - M);
  __syncthreads();

  // contiguous bases: left children rows (s,u) u=s+1..s+K; right rows (u,e)
  const short* baseL = E_L + ((size_t)((b*NP1 + s)*NP1 + s + 1)) * S;
  const short* baseR = E_R + ((size_t)((b*NP1 + e)*NP1 + s + 1)) * S;

  // staging: thread handles (k-quad kq, i-pair j) -> 4 x ds_write_b64
  int items = (Kpad >> 2) * 48;
  for (int idx = tid; idx < items; idx += 256){
    int kq = idx / 48, j = idx - kq * 48;
    int i = 2 * j;
    s16x4 el0 = {0,0,0,0}, el1 = {0,0,0,0}, er0 = {0,0,0,0}, er1 = {0,0,0,0};
    if (j < 45){
      #pragma unroll
      for (int kk = 0; kk < 4; ++kk){
        int k = 4*kq + kk;
        if (k < K){
          bool lOK = (k == 0)     ? (j >= 15) : (j < 15);
          bool rOK = (k == K - 1) ? (j >= 15) : (j < 15);
          float ck = cK[k];
          if (lOK){
            float f0, f1;
            if (hasInline && k == K - 1){
              float inv = 1.f / cmax[0];
              f0 = qs[0][i] * inv * ck;
              f1 = qs[0][i+1] * inv * ck;
            } else {
              unsigned int L = *(const unsigned int*)(baseL + k*S + i);
              f0 = __uint_as_float(L << 16) * ck;
              f1 = __uint_as_float(L & 0xFFFF0000u) * ck;
            }
            el0[kk] = f2bs(f0);
            el1[kk] = f2bs(f1);
          }
          if (rOK){
            if (hasInline && k == 0){
              float inv = 1.f / cmax[1];
              er0[kk] = f2bs(qs[1][i] * inv);
              er1[kk] = f2bs(qs[1][i+1] * inv);
            } else {
              unsigned int R = *(const unsigned int*)(baseR + k*S + i);
              er0[kk] = (short)(R & 0xFFFFu);
              er1[kk] = (short)(R >> 16);
            }
          }
        }
      }
    }
    // swizzled position: block (kbase>>3) ^ (j & kmask); sub-offset kbase&7
    int kbase = 4 * kq;
    int swp = ((((kbase >> 3) ^ (j & kmask)) << 3) + (kbase & 7));
    *(s16x4*)&elT[i*S1STR + swp]     = el0;
    *(s16x4*)&elT[(i+1)*S1STR + swp] = el1;
    *(s16x4*)&erT[i*S1STR + swp]     = er0;
    *(s16x4*)&erT[(i+1)*S1STR + swp] = er1;
  }
  __syncthreads();

  int wid = tid >> 6, lane = tid & 63;
  int rr = lane & 15, hi = lane >> 4;
  int ksteps = Kpad >> 5;
  f32x4 accs[9];
  #pragma unroll
  for (int j = 0; j < 9; ++j){           // 36 tiles over 4 waves
    int t = wid * 9 + j;
    int tr = t / 6, tc = t - tr * 6;
    int ar = tr*16 + rr, br = tc*16 + rr;
    f32x4 acc = {0.f, 0.f, 0.f, 0.f};
    for (int ks = 0; ks < ksteps; ++ks){
      int kb = ks*4 + hi;
      bf16x8 af = *(bf16x8*)&elT[ar*S1STR + ((kb ^ ((ar >> 1) & kmask)) << 3)];
      bf16x8 bf2 = *(bf16x8*)&erT[br*S1STR + ((kb ^ ((br >> 1) & kmask)) << 3)];
      acc = __builtin_amdgcn_mfma_f32_16x16x32_bf16(af, bf2, acc, 0, 0, 0);
    }
    accs[j] = acc;
  }
  __syncthreads();                        // all elT/erT reads done; sbuf reusable

  // repack: fp8 O tile, linear [l*96 + r] bytes in sbuf, then uint4 stores
  unsigned char* rep = (unsigned char*)sbuf;
  for (int idx = tid; idx < S * (KP - S); idx += 256){
    int l = idx / (KP - S), c = idx - l * (KP - S);
    rep[l*KP + S + c] = 0;
  }
  #pragma unroll
  for (int j = 0; j < 9; ++j){
    int t = wid * 9 + j;
    int tr = t / 6, tc = t - tr * 6;
    int rcol = tc*16 + rr;
    if (rcol < S){
      unsigned int pk = pk4_e4m3(accs[j][0], accs[j][1], accs[j][2], accs[j][3]);
      #pragma unroll
      for (int q = 0; q < 4; ++q){
        int l = tr*16 + hi*4 + q;
        if (l < S) rep[l*KP + rcol] = (unsigned char)((pk >> (8*q)) & 0xff);
      }
    }
  }
  __syncthreads();

  size_t obase = ((size_t)(b*NSMAX + s)) * KK;
  uint4* dst = (uint4*)(Og8 + obase);
  const uint4* src = (const uint4*)rep;
  for (int i = tid; i < KK/16; i += 256) dst[i] = src[i];
}

// fp8 MFMA split-K GEMM; no LDS zero-fill (clamped rows -> discarded slots).
__global__ __launch_bounds__(512) void stage2(int ns, int ntiles,
                                              const unsigned char* __restrict__ erule8,
                                              const unsigned char* __restrict__ Og8,
                                              float* __restrict__ Cpart){
  int kc = blockIdx.x, b = blockIdx.y, tid = threadIdx.x;
  __shared__ __align__(16) unsigned char ldsb[2 * MTOTB];   // 13.8 KB (dbuf)
  int wid = tid >> 6, lane = tid & 63;
  int mt = wid & 1, nt = wid >> 1;
  f32x4 acc = {0.f, 0.f, 0.f, 0.f};

  int slot = tid & 7;
  int aRow = (tid >> 3) & 31;
  int aRowS = aRow < NT ? aRow : NT - 1;      // clamp: rows 30,31 replicate 29
  bool aDo = (tid < 256);
  int bRow = tid >> 3;
  int bRowS = bRow < ns ? bRow : ns - 1;      // clamp
  const unsigned char* aSrc = erule8 + ((size_t)(b*NT + aRowS)) * KK + slot * 8;
  const unsigned char* bSrc = Og8    + ((size_t)(b*NSMAX + bRowS)) * KK + slot * 8;
  int aOff = aRow * ROWB + slot * 8;
  int bOff = AOFFB + bRow * ROWB + slot * 8;

  int arow = mt*16 + (lane & 15);
  int brow = nt*16 + (lane & 15);
  int hi = lane >> 4;
  bool active = nt < ntiles;
  int t0 = kc * TPC;

  uint2 ra, rb;
  if (aDo) ra = *(const uint2*)(aSrc + (size_t)t0 * KT2B);
  rb = *(const uint2*)(bSrc + (size_t)t0 * KT2B);

  int cur = 0;
  for (int tt = 0; tt < TPC; ++tt){
    if (aDo) *(uint2*)&ldsb[cur*MTOTB + aOff] = ra;
    *(uint2*)&ldsb[cur*MTOTB + bOff] = rb;
    if (tt + 1 < TPC){
      size_t koff = (size_t)(t0 + tt + 1) * KT2B;
      if (aDo) ra = *(const uint2*)(aSrc + koff);
      rb = *(const uint2*)(bSrc + koff);
    }
    __syncthreads();   // buf[cur] staged; compute(tt-1) on buf[cur^1] done
    if (active){
      #pragma unroll
      for (int ks = 0; ks < 2; ++ks){
        int sb = ks*4 + hi;
        long af = *(const long*)&ldsb[cur*MTOTB + arow*ROWB + sb*8];
        long bf2 = *(const long*)&ldsb[cur*MTOTB + AOFFB + brow*ROWB + sb*8];
        acc = __builtin_amdgcn_mfma_f32_16x16x32_fp8_fp8(af, bf2, acc, 0, 0, 0);
      }
    }
    cur ^= 1;
  }

  if (active){
    int scol = nt*16 + (lane & 15);
    if (scol < ns){
      int p0 = mt*16 + hi*4;           // acc[r] -> p = p0 + r (contiguous)
      float* cp = Cpart + ((size_t)(kc*B + b)) * CELLSP + scol*32 + p0;
      *(f32x4*)cp = acc;               // p=30,31 overflow lands in padding
    }
  }
}

// Root: beta(w=50) computed directly from Cpart (ns=1: cell = p).
__global__ void root_lse(const float* __restrict__ Cpart, const float* __restrict__ Mbuf,
                         const float* __restrict__ m_rule, const float* __restrict__ root,
                         float* __restrict__ out){
  int b = blockIdx.x, j = threadIdx.x;
  float v = NEGF;
  if (j < NT){
    float sum = 0.f;
    #pragma unroll
    for (int q = 0; q < KSPL; ++q)
      sum += Cpart[((size_t)(q*B + b))*CELLSP + j];
    v = __logf(fmaxf(sum, 1e-37f)) + Mbuf[b*NSMAX + 0]
      + m_rule[b*NT + j] + root[b*NT + j];
  }
  float m = v;
  #pragma unroll
  for (int off = 32; off > 0; off >>= 1) m = fmaxf(m, __shfl_xor(m, off));
  float ex = __expf(v - m);
  #pragma unroll
  for (int off = 32; off > 0; off >>= 1) ex += __shfl_xor(ex, off);
  if (j == 0) out[b] = __logf(ex) + m;
}

} // namespace

extern "C" void kernel_launch(void* const* d_in, const int* in_sizes, int n_in,
                              void* d_out, int out_size, void* d_ws, size_t ws_size,
                              hipStream_t stream){
  (void)in_sizes; (void)n_in; (void)out_size; (void)ws_size;
  const float* unary = (const float*)d_in[0];
  const float* rule  = (const float*)d_in[1];
  const float* root  = (const float*)d_in[2];

  char* ws = (char*)d_ws;
  size_t off = 0;
  auto alloc = [&](size_t bytes) -> void* {
    void* p = ws + off;
    off += (bytes + 255) & ~(size_t)255;
    return p;
  };
  float* mb     = (float*)alloc(sizeof(float) * (size_t)B * NP1 * NP1);
  float* mbT    = (float*)alloc(sizeof(float) * (size_t)B * NP1 * NP1);
  float* m_rule = (float*)alloc(sizeof(float) * B * NT);
  float* emr    = (float*)alloc(sizeof(float) * B * NT);
  float* Mbuf   = (float*)alloc(sizeof(float) * 2 * B * NSMAX);   // parity dbuf
  float* Cpart  = (float*)alloc(sizeof(float) * KSPL * B * CELLSP);  // 6.1 MB
  short* E_L    = (short*)alloc(sizeof(short) * (size_t)ECOUNT);     // 30 MB
  short* E_R    = (short*)alloc(sizeof(short) * (size_t)ECOUNT);     // 30 MB
  unsigned char* erule8 = (unsigned char*)alloc((size_t)B * NT * KK);    // 16.6 MB
  unsigned char* Og8    = (unsigned char*)alloc((size_t)B * NSMAX * KK); // 27.1 MB

  unary_init<<<dim3(N, B), dim3(64), 0, stream>>>(unary, mb, mbT, E_L, E_R);
  rule_prep<<<dim3(NT, B), dim3(256), 0, stream>>>(rule, m_rule, emr, erule8);

  for (int w = 2; w <= N; ++w){
    int ns = N - w + 1;
    int ntiles = (ns + 15) >> 4;
    const float* mprev = Mbuf + ((size_t)((w - 1) & 1)) * B * NSMAX;
    float*       mcur  = Mbuf + ((size_t)(w & 1)) * B * NSMAX;
    stage1<<<dim3(ns, B), dim3(256), 0, stream>>>(w, ns, Cpart, emr,
                                                  mprev, mcur, E_L, E_R, mb, mbT, Og8);
    stage2<<<dim3(KSPL, B), dim3(512), 0, stream>>>(ns, ntiles, erule8, Og8, Cpart);
  }
  // w=50 parity: 50&1 == 0 -> Mbuf first half holds M for width 50
  root_lse<<<dim3(B), dim3(64), 0, stream>>>(Cpart, Mbuf, m_rule, root, (float*)d_out);
}

// Round 23
// 1350.990 us; speedup vs baseline: 1.1595x; 1.0428x over previous
//
#include <hip/hip_runtime.h>
#include <hip/hip_bf16.h>

#define NEGF (-1000000000.0f)

namespace {

constexpr int B  = 64;
constexpr int N  = 50;
constexpr int NT = 30;
constexpr int T  = 60;
constexpr int S  = 90;          // NT + T
constexpr int NP1 = N + 1;      // 51
constexpr int NSMAX = N - 1;    // 49
constexpr int SS = S * S;       // 8100
constexpr int CELLSP = NSMAX * 32 + 32;  // padded cells (stride 32 per span)
constexpr int ECOUNT = B * NP1 * NP1 * S;

// ---- padded K layout (BYTES: fp8 = 1 B/element) ----
constexpr int KP  = 96;          // padded r-dim per l (pads are exact 0)
constexpr int KK  = S * KP;      // 8640 elements = bytes
constexpr int KSPL = 15;         // split-K chunks
constexpr int KT2B = 64;         // K-tile bytes per row slice
constexpr int NKT = KK / KT2B;   // 135
constexpr int TPC = NKT / KSPL;  // 9 tiles per chunk
constexpr int ROWB  = 72;        // stage2 LDS row stride bytes
constexpr int AOFFB = 32 * ROWB;
constexpr int MTOTB = (32 + 64) * ROWB;       // 6912 B per buffer

constexpr int S1R = 96;          // stage1 padded state rows: 6 tiles of 16

using bf16x8 = __attribute__((ext_vector_type(8))) short;
using s16x4  = __attribute__((ext_vector_type(4))) short;
using f32x4  = __attribute__((ext_vector_type(4))) float;

__device__ __forceinline__ unsigned int pk4_e4m3(float a, float b, float c, float d){
  int w = __builtin_amdgcn_cvt_pk_fp8_f32(a, b, 0, false);
  w = __builtin_amdgcn_cvt_pk_fp8_f32(c, d, w, true);
  return (unsigned int)w;
}
__device__ __forceinline__ short f2bs(float v){
  __hip_bfloat16 h = __float2bfloat16(v);
  return *reinterpret_cast<short*>(&h);
}

// width-1 spans: mb/mbT = state max; E_L/E_R = bf16(exp(unary - mb)).
__global__ void unary_init(const float* __restrict__ unary, float* __restrict__ mb,
                           float* __restrict__ mbT,
                           short* __restrict__ E_L, short* __restrict__ E_R){
  int k = blockIdx.x, b = blockIdx.y, j = threadIdx.x;
  float v = (j < T) ? unary[(b*N + k)*T + j] : NEGF;
  float m = v;
  #pragma unroll
  for (int off = 32; off > 0; off >>= 1) m = fmaxf(m, __shfl_xor(m, off));
  if (j == 0){
    mb [(b*NP1 + k)*NP1 + (k+1)] = m;
    mbT[(b*NP1 + (k+1))*NP1 + k] = m;
  }
  if (j < T){
    short sv = f2bs(__expf(v - m));
    E_L[((size_t)((b*NP1 + k)*NP1 + (k+1)))*S + NT + j] = sv;
    E_R[((size_t)((b*NP1 + (k+1))*NP1 + k))*S + NT + j] = sv;
  }
}

// 2-pass rule prep -> fp8 e4m3; emr = exp(m_rule) for stage1's inline finalize.
__global__ __launch_bounds__(256) void rule_prep(const float* __restrict__ rule,
                                                 float* __restrict__ m_rule,
                                                 float* __restrict__ emr,
                                                 unsigned char* __restrict__ erule8){
  int p = blockIdx.x, b = blockIdx.y, tid = threadIdx.x;
  size_t base = (size_t)(b*NT + p) * SS;
  size_t obase = (size_t)(b*NT + p) * KK;
  const float4* r4 = (const float4*)(rule + base);
  float lm = NEGF;
  for (int i = tid; i < SS/4; i += 256){
    float4 v = r4[i];
    lm = fmaxf(fmaxf(lm, fmaxf(v.x, v.y)), fmaxf(v.z, v.w));
  }
  #pragma unroll
  for (int off = 32; off > 0; off >>= 1) lm = fmaxf(lm, __shfl_xor(lm, off));
  __shared__ float wmax[4];
  __shared__ float sm;
  if ((tid & 63) == 0) wmax[tid >> 6] = lm;
  __syncthreads();
  if (tid == 0){
    float m = fmaxf(fmaxf(wmax[0], wmax[1]), fmaxf(wmax[2], wmax[3]));
    m_rule[b*NT + p] = m;
    emr[b*NT + p] = __expf(m);
    sm = m;
  }
  __syncthreads();
  float m = sm;
  for (int idx = tid; idx < S * 24; idx += 256){
    int l = idx / 24, q4 = idx - l * 24;
    int r = q4 * 4;
    float e[4];
    #pragma unroll
    for (int j = 0; j < 4; ++j){
      int rr = r + j;
      e[j] = (rr < S) ? __expf(rule[base + l*S + rr] - m) : 0.f;
    }
    *(unsigned int*)&erule8[obase + l*KP + r] = pk4_e4m3(e[0], e[1], e[2], e[3]);
  }
}

// Per span (b,s) of width w: O[l,r] = sum_k el[k,l]*er[k,r] via bf16 MFMA.
// R23: templated on (KPAD,SSTR). Variant A (w<=33): KPAD=32, SSTR=40 ->
// sbuf 15.4KB -> 8 blocks/CU (was 5). Variant B (w>33): KPAD=64, SSTR=72.
template<int KPAD, int SSTR>
__global__ __launch_bounds__(256) void stage1(int w, int ns,
                                              const float* __restrict__ Cpart,
                                              const float* __restrict__ emr,
                                              const float* __restrict__ MbufPrev,
                                              float* __restrict__ MbufCur,
                                              short* __restrict__ E_L,
                                              short* __restrict__ E_R,
                                              float* __restrict__ mb,
                                              float* __restrict__ mbT,
                                              unsigned char* __restrict__ Og8){
  constexpr int KMASK = (KPAD >> 3) - 1;   // 3 or 7
  constexpr int KSTEPS = KPAD >> 5;        // 1 or 2
  int s = blockIdx.x, b = blockIdx.y, e = s + w, tid = threadIdx.x;
  int K = w - 1;
  __shared__ float stmp[NSMAX];
  __shared__ float cK[NSMAX];
  __shared__ float sM;
  __shared__ float qs[2][32];
  __shared__ float cmax[2];
  __shared__ float cmb[2];
  __shared__ __align__(16) short sbuf[2 * S1R * SSTR];
  short* elT = sbuf;
  short* erT = sbuf + S1R * SSTR;

  bool hasInline = (w >= 3);
  if (hasInline){
    // inline finalize of width-(w-1) cells sp=s (c=0) and sp=s+1 (c=1)
    for (int idx = tid; idx < 2*NT; idx += 256){
      int c = (idx >= NT) ? 1 : 0;
      int p = idx - c*NT;
      int sp = s + c;
      float sum = 0.f;
      #pragma unroll
      for (int kc = 0; kc < KSPL; ++kc)
        sum += Cpart[((size_t)(kc*B + b))*CELLSP + sp*32 + p];
      qs[c][p] = sum * emr[b*NT + p];
    }
  }
  __syncthreads();
  if (hasInline && tid < 64){
    // lanes 0-31 reduce qs[0], lanes 32-63 reduce qs[1] (xor offsets < 32)
    int half = tid >> 5, p = tid & 31;
    float v = (p < NT) ? qs[half][p] : 1e-37f;
    #pragma unroll
    for (int off = 16; off > 0; off >>= 1) v = fmaxf(v, __shfl_xor(v, off));
    if (p == 0){
      cmax[half] = v;
      cmb[half] = MbufPrev[b*NSMAX + (s + half)] + __logf(v);
    }
  }
  __syncthreads();

  if (hasInline){
    // writer duty for future launches (values deterministic across blocks)
    int wp = w - 1;
    if (tid < 15){
      float inv = 1.f / cmax[0];
      unsigned int pk = (unsigned int)(unsigned short)f2bs(qs[0][2*tid] * inv) |
                        ((unsigned int)(unsigned short)f2bs(qs[0][2*tid+1] * inv) << 16);
      *(unsigned int*)&E_L[((size_t)((b*NP1 + s)*NP1 + s + wp))*S + 2*tid] = pk;
      *(unsigned int*)&E_R[((size_t)((b*NP1 + s + wp)*NP1 + s))*S + 2*tid] = pk;
    } else if (tid >= 32 && tid < 47 && s == ns - 1){
      int t2 = tid - 32;
      float inv = 1.f / cmax[1];
      unsigned int pk = (unsigned int)(unsigned short)f2bs(qs[1][2*t2] * inv) |
                        ((unsigned int)(unsigned short)f2bs(qs[1][2*t2+1] * inv) << 16);
      *(unsigned int*)&E_L[((size_t)((b*NP1 + s + 1)*NP1 + s + 1 + wp))*S + 2*t2] = pk;
      *(unsigned int*)&E_R[((size_t)((b*NP1 + s + 1 + wp)*NP1 + s + 1))*S + 2*t2] = pk;
    }
    if (tid == 0){
      mb [(b*NP1 + s)*NP1 + (s + wp)] = cmb[0];
      mbT[(b*NP1 + s + wp)*NP1 + s]   = cmb[0];
    }
    if (tid == 16 && s == ns - 1){
      mb [(b*NP1 + s + 1)*NP1 + (s + 1 + wp)] = cmb[1];
      mbT[(b*NP1 + s + 1 + wp)*NP1 + (s + 1)] = cmb[1];
    }
  }

  if (tid < K){
    int u = s + tid + 1;
    // both gathers contiguous in u: mb row s, mbT row e
    float ml = (hasInline && tid == K - 1) ? cmb[0] : mb [(b*NP1 + s)*NP1 + u];
    float mr = (hasInline && tid == 0)     ? cmb[1] : mbT[(b*NP1 + e)*NP1 + u];
    stmp[tid] = ml + mr;
  }
  __syncthreads();
  if (tid < 64){
    float v = (tid < K) ? stmp[tid] : NEGF;
    #pragma unroll
    for (int off = 32; off > 0; off >>= 1) v = fmaxf(v, __shfl_xor(v, off));
    if (tid == 0){
      sM = v;
      MbufCur[b*NSMAX + s] = v;
    }
  }
  __syncthreads();
  float M = sM;
  if (tid < K) cK[tid] = __expf(stmp[tid] - M);
  __syncthreads();

  // contiguous bases: left children rows (s,u) u=s+1..s+K; right rows (u,e)
  const short* baseL = E_L + ((size_t)((b*NP1 + s)*NP1 + s + 1)) * S;
  const short* baseR = E_R + ((size_t)((b*NP1 + e)*NP1 + s + 1)) * S;

  // staging: thread handles (k-quad kq, i-pair j) -> 4 x ds_write_b64
  int items = (KPAD >> 2) * 48;
  for (int idx = tid; idx < items; idx += 256){
    int kq = idx / 48, j = idx - kq * 48;
    int i = 2 * j;
    s16x4 el0 = {0,0,0,0}, el1 = {0,0,0,0}, er0 = {0,0,0,0}, er1 = {0,0,0,0};
    if (j < 45){
      #pragma unroll
      for (int kk = 0; kk < 4; ++kk){
        int k = 4*kq + kk;
        if (k < K){
          bool lOK = (k == 0)     ? (j >= 15) : (j < 15);
          bool rOK = (k == K - 1) ? (j >= 15) : (j < 15);
          float ck = cK[k];
          if (lOK){
            float f0, f1;
            if (hasInline && k == K - 1){
              float inv = 1.f / cmax[0];
              f0 = qs[0][i] * inv * ck;
              f1 = qs[0][i+1] * inv * ck;
            } else {
              unsigned int L = *(const unsigned int*)(baseL + k*S + i);
              f0 = __uint_as_float(L << 16) * ck;
              f1 = __uint_as_float(L & 0xFFFF0000u) * ck;
            }
            el0[kk] = f2bs(f0);
            el1[kk] = f2bs(f1);
          }
          if (rOK){
            if (hasInline && k == 0){
              float inv = 1.f / cmax[1];
              er0[kk] = f2bs(qs[1][i] * inv);
              er1[kk] = f2bs(qs[1][i+1] * inv);
            } else {
              unsigned int R = *(const unsigned int*)(baseR + k*S + i);
              er0[kk] = (short)(R & 0xFFFFu);
              er1[kk] = (short)(R >> 16);
            }
          }
        }
      }
    }
    // swizzled position: block (kbase>>3) ^ (j & KMASK); sub-offset kbase&7
    int kbase = 4 * kq;
    int swp = ((((kbase >> 3) ^ (j & KMASK)) << 3) + (kbase & 7));
    *(s16x4*)&elT[i*SSTR + swp]     = el0;
    *(s16x4*)&elT[(i+1)*SSTR + swp] = el1;
    *(s16x4*)&erT[i*SSTR + swp]     = er0;
    *(s16x4*)&erT[(i+1)*SSTR + swp] = er1;
  }
  __syncthreads();

  int wid = tid >> 6, lane = tid & 63;
  int rr = lane & 15, hi = lane >> 4;
  f32x4 accs[9];
  #pragma unroll
  for (int j = 0; j < 9; ++j){           // 36 tiles over 4 waves
    int t = wid * 9 + j;
    int tr = t / 6, tc = t - tr * 6;
    int ar = tr*16 + rr, br = tc*16 + rr;
    f32x4 acc = {0.f, 0.f, 0.f, 0.f};
    #pragma unroll
    for (int ks = 0; ks < KSTEPS; ++ks){
      int kb = ks*4 + hi;
      bf16x8 af = *(bf16x8*)&elT[ar*SSTR + ((kb ^ ((ar >> 1) & KMASK)) << 3)];
      bf16x8 bf2 = *(bf16x8*)&erT[br*SSTR + ((kb ^ ((br >> 1) & KMASK)) << 3)];
      acc = __builtin_amdgcn_mfma_f32_16x16x32_bf16(af, bf2, acc, 0, 0, 0);
    }
    accs[j] = acc;
  }
  __syncthreads();                        // all elT/erT reads done; sbuf reusable

  // repack: fp8 O tile, linear [l*96 + r] bytes in sbuf, then uint4 stores
  unsigned char* rep = (unsigned char*)sbuf;
  for (int idx = tid; idx < S * (KP - S); idx += 256){
    int l = idx / (KP - S), c = idx - l * (KP - S);
    rep[l*KP + S + c] = 0;
  }
  #pragma unroll
  for (int j = 0; j < 9; ++j){
    int t = wid * 9 + j;
    int tr = t / 6, tc = t - tr * 6;
    int rcol = tc*16 + rr;
    if (rcol < S){
      unsigned int pk = pk4_e4m3(accs[j][0], accs[j][1], accs[j][2], accs[j][3]);
      #pragma unroll
      for (int q = 0; q < 4; ++q){
        int l = tr*16 + hi*4 + q;
        if (l < S) rep[l*KP + rcol] = (unsigned char)((pk >> (8*q)) & 0xff);
      }
    }
  }
  __syncthreads();

  size_t obase = ((size_t)(b*NSMAX + s)) * KK;
  uint4* dst = (uint4*)(Og8 + obase);
  const uint4* src = (const uint4*)rep;
  for (int i = tid; i < KK/16; i += 256) dst[i] = src[i];
}

// fp8 MFMA split-K GEMM; no LDS zero-fill (clamped rows -> discarded slots).
__global__ __launch_bounds__(512) void stage2(int ns, int ntiles,
                                              const unsigned char* __restrict__ erule8,
                                              const unsigned char* __restrict__ Og8,
                                              float* __restrict__ Cpart){
  int kc = blockIdx.x, b = blockIdx.y, tid = threadIdx.x;
  __shared__ __align__(16) unsigned char ldsb[2 * MTOTB];   // 13.8 KB (dbuf)
  int wid = tid >> 6, lane = tid & 63;
  int mt = wid & 1, nt = wid >> 1;
  f32x4 acc = {0.f, 0.f, 0.f, 0.f};

  int slot = tid & 7;
  int aRow = (tid >> 3) & 31;
  int aRowS = aRow < NT ? aRow : NT - 1;      // clamp: rows 30,31 replicate 29
  bool aDo = (tid < 256);
  int bRow = tid >> 3;
  int bRowS = bRow < ns ? bRow : ns - 1;      // clamp
  const unsigned char* aSrc = erule8 + ((size_t)(b*NT + aRowS)) * KK + slot * 8;
  const unsigned char* bSrc = Og8    + ((size_t)(b*NSMAX + bRowS)) * KK + slot * 8;
  int aOff = aRow * ROWB + slot * 8;
  int bOff = AOFFB + bRow * ROWB + slot * 8;

  int arow = mt*16 + (lane & 15);
  int brow = nt*16 + (lane & 15);
  int hi = lane >> 4;
  bool active = nt < ntiles;
  int t0 = kc * TPC;

  uint2 ra, rb;
  if (aDo) ra = *(const uint2*)(aSrc + (size_t)t0 * KT2B);
  rb = *(const uint2*)(bSrc + (size_t)t0 * KT2B);

  int cur = 0;
  for (int tt = 0; tt < TPC; ++tt){
    if (aDo) *(uint2*)&ldsb[cur*MTOTB + aOff] = ra;
    *(uint2*)&ldsb[cur*MTOTB + bOff] = rb;
    if (tt + 1 < TPC){
      size_t koff = (size_t)(t0 + tt + 1) * KT2B;
      if (aDo) ra = *(const uint2*)(aSrc + koff);
      rb = *(const uint2*)(bSrc + koff);
    }
    __syncthreads();   // buf[cur] staged; compute(tt-1) on buf[cur^1] done
    if (active){
      #pragma unroll
      for (int ks = 0; ks < 2; ++ks){
        int sb = ks*4 + hi;
        long af = *(const long*)&ldsb[cur*MTOTB + arow*ROWB + sb*8];
        long bf2 = *(const long*)&ldsb[cur*MTOTB + AOFFB + brow*ROWB + sb*8];
        acc = __builtin_amdgcn_mfma_f32_16x16x32_fp8_fp8(af, bf2, acc, 0, 0, 0);
      }
    }
    cur ^= 1;
  }

  if (active){
    int scol = nt*16 + (lane & 15);
    if (scol < ns){
      int p0 = mt*16 + hi*4;           // acc[r] -> p = p0 + r (contiguous)
      float* cp = Cpart + ((size_t)(kc*B + b)) * CELLSP + scol*32 + p0;
      *(f32x4*)cp = acc;               // p=30,31 overflow lands in padding
    }
  }
}

// Root: beta(w=50) computed directly from Cpart (ns=1: cell = p).
__global__ void root_lse(const float* __restrict__ Cpart, const float* __restrict__ Mbuf,
                         const float* __restrict__ m_rule, const float* __restrict__ root,
                         float* __restrict__ out){
  int b = blockIdx.x, j = threadIdx.x;
  float v = NEGF;
  if (j < NT){
    float sum = 0.f;
    #pragma unroll
    for (int q = 0; q < KSPL; ++q)
      sum += Cpart[((size_t)(q*B + b))*CELLSP + j];
    v = __logf(fmaxf(sum, 1e-37f)) + Mbuf[b*NSMAX + 0]
      + m_rule[b*NT + j] + root[b*NT + j];
  }
  float m = v;
  #pragma unroll
  for (int off = 32; off > 0; off >>= 1) m = fmaxf(m, __shfl_xor(m, off));
  float ex = __expf(v - m);
  #pragma unroll
  for (int off = 32; off > 0; off >>= 1) ex += __shfl_xor(ex, off);
  if (j == 0) out[b] = __logf(ex) + m;
}

} // namespace

extern "C" void kernel_launch(void* const* d_in, const int* in_sizes, int n_in,
                              void* d_out, int out_size, void* d_ws, size_t ws_size,
                              hipStream_t stream){
  (void)in_sizes; (void)n_in; (void)out_size; (void)ws_size;
  const float* unary = (const float*)d_in[0];
  const float* rule  = (const float*)d_in[1];
  const float* root  = (const float*)d_in[2];

  char* ws = (char*)d_ws;
  size_t off = 0;
  auto alloc = [&](size_t bytes) -> void* {
    void* p = ws + off;
    off += (bytes + 255) & ~(size_t)255;
    return p;
  };
  float* mb     = (float*)alloc(sizeof(float) * (size_t)B * NP1 * NP1);
  float* mbT    = (float*)alloc(sizeof(float) * (size_t)B * NP1 * NP1);
  float* m_rule = (float*)alloc(sizeof(float) * B * NT);
  float* emr    = (float*)alloc(sizeof(float) * B * NT);
  float* Mbuf   = (float*)alloc(sizeof(float) * 2 * B * NSMAX);   // parity dbuf
  float* Cpart  = (float*)alloc(sizeof(float) * KSPL * B * CELLSP);  // 6.1 MB
  short* E_L    = (short*)alloc(sizeof(short) * (size_t)ECOUNT);     // 30 MB
  short* E_R    = (short*)alloc(sizeof(short) * (size_t)ECOUNT);     // 30 MB
  unsigned char* erule8 = (unsigned char*)alloc((size_t)B * NT * KK);    // 16.6 MB
  unsigned char* Og8    = (unsigned char*)alloc((size_t)B * NSMAX * KK); // 27.1 MB

  unary_init<<<dim3(N, B), dim3(64), 0, stream>>>(unary, mb, mbT, E_L, E_R);
  rule_prep<<<dim3(NT, B), dim3(256), 0, stream>>>(rule, m_rule, emr, erule8);

  for (int w = 2; w <= N; ++w){
    int ns = N - w + 1;
    int ntiles = (ns + 15) >> 4;
    const float* mprev = Mbuf + ((size_t)((w - 1) & 1)) * B * NSMAX;
    float*       mcur  = Mbuf + ((size_t)(w & 1)) * B * NSMAX;
    if (w <= 33)
      stage1<32, 40><<<dim3(ns, B), dim3(256), 0, stream>>>(w, ns, Cpart, emr,
                                                  mprev, mcur, E_L, E_R, mb, mbT, Og8);
    else
      stage1<64, 72><<<dim3(ns, B), dim3(256), 0, stream>>>(w, ns, Cpart, emr,
                                                  mprev, mcur, E_L, E_R, mb, mbT, Og8);
    stage2<<<dim3(KSPL, B), dim3(512), 0, stream>>>(ns, ntiles, erule8, Og8, Cpart);
  }
  // w=50 parity: 50&1 == 0 -> Mbuf first half holds M for width 50
  root_lse<<<dim3(B), dim3(64), 0, stream>>>(Cpart, Mbuf, m_rule, root, (float*)d_out);
}